// Round 1
// baseline (147.457 us; speedup 1.0000x reference)
//
#include <hip/hip_runtime.h>

// Problem constants
#define NB 8192   // batch
#define ND 512    // feature dim
#define NC 512    // num classes
#define MARGIN_F 1.0f

// ws layout (4-byte units):
// [0,512)       counts (uint)        -- memset 0
// [512,1024)    csq (float)          -- written by k1
// [1024,9216)   negmin keys (uint)   -- memset 0xFF
// [9216,17408)  apval (float)        -- one writer per row in k2
// [17408,25600) rowloss (float)
// [25600,33792) rowprec (float)

__device__ __forceinline__ unsigned fkey(float f) {
    unsigned u = __float_as_uint(f);
    unsigned mask = (u & 0x80000000u) ? 0xFFFFFFFFu : 0x80000000u;
    return u ^ mask;
}
__device__ __forceinline__ float finv(unsigned k) {
    unsigned mask = (k & 0x80000000u) ? 0x80000000u : 0xFFFFFFFFu;
    return __uint_as_float(k ^ mask);
}

// Kernel 1: center sqnorms (wave per center) + target histogram.
__global__ __launch_bounds__(256) void k1_prep(const float* __restrict__ centers,
                                               const int* __restrict__ targets,
                                               unsigned* __restrict__ counts,
                                               float* __restrict__ csq) {
    const int tid  = threadIdx.x;
    const int wave = tid >> 6;
    const int lane = tid & 63;
    const int c = blockIdx.x * 4 + wave;   // grid=128 -> 512 centers
    const float4* row = (const float4*)&centers[(size_t)c * ND];
    float4 v1 = row[lane];
    float4 v2 = row[lane + 64];
    float s = v1.x*v1.x + v1.y*v1.y + v1.z*v1.z + v1.w*v1.w
            + v2.x*v2.x + v2.y*v2.y + v2.z*v2.z + v2.w*v2.w;
    #pragma unroll
    for (int off = 32; off > 0; off >>= 1) s += __shfl_down(s, off);
    if (lane == 0) csq[c] = s;
    if (tid < 64) {
        int t = targets[blockIdx.x * 64 + tid];  // 128*64 = 8192 targets
        atomicAdd(&counts[t], 1u);
    }
}

// Kernel 2: fused SGEMM + masked-min epilogue.
// Tile: 64 rows x 64 centers per block, BK=32, 256 threads, 4x4 micro-tile.
// grid = (8 ctiles, 128 rowtiles)
__global__ __launch_bounds__(256) void k2_gemm_min(const float* __restrict__ inputs,
                                                   const int* __restrict__ targets,
                                                   const float* __restrict__ centers,
                                                   const unsigned* __restrict__ counts,
                                                   const float* __restrict__ csq,
                                                   unsigned* __restrict__ negmin,
                                                   float* __restrict__ apval) {
    __shared__ __align__(16) float As[32 * 68];   // [k][m], stride 68
    __shared__ __align__(16) float Bs[32 * 68];   // [k][n], stride 68
    __shared__ unsigned ldsmin[64];

    const int tid = threadIdx.x;
    const int tx = tid & 15;      // -> 4 center cols
    const int ty = tid >> 4;      // -> 4 rows
    const int rbase = blockIdx.y * 64;
    const int cbase = blockIdx.x * 64;

    const int lrow = tid >> 3;          // 0..31
    const int lk4  = (tid & 7) << 2;    // 0,4,...,28

    float acc[4][4] = {};

    for (int kb = 0; kb < ND; kb += 32) {
        __syncthreads();
        #pragma unroll
        for (int p = 0; p < 2; ++p) {
            int row = lrow + p * 32;
            float4 va = *(const float4*)&inputs [(size_t)(rbase + row) * ND + kb + lk4];
            float4 vb = *(const float4*)&centers[(size_t)(cbase + row) * ND + kb + lk4];
            As[(lk4 + 0) * 68 + row] = va.x;
            As[(lk4 + 1) * 68 + row] = va.y;
            As[(lk4 + 2) * 68 + row] = va.z;
            As[(lk4 + 3) * 68 + row] = va.w;
            Bs[(lk4 + 0) * 68 + row] = vb.x;
            Bs[(lk4 + 1) * 68 + row] = vb.y;
            Bs[(lk4 + 2) * 68 + row] = vb.z;
            Bs[(lk4 + 3) * 68 + row] = vb.w;
        }
        __syncthreads();
        #pragma unroll
        for (int k = 0; k < 32; ++k) {
            float4 a = *(const float4*)&As[k * 68 + ty * 4];
            float4 b = *(const float4*)&Bs[k * 68 + tx * 4];
            float av[4] = {a.x, a.y, a.z, a.w};
            float bv[4] = {b.x, b.y, b.z, b.w};
            #pragma unroll
            for (int i = 0; i < 4; ++i)
                #pragma unroll
                for (int j = 0; j < 4; ++j)
                    acc[i][j] = fmaf(av[i], bv[j], acc[i][j]);
        }
    }

    // Epilogue: per-row masked min over this block's 64 centers + ap capture.
    __syncthreads();
    if (tid < 64) ldsmin[tid] = 0xFFFFFFFFu;
    __syncthreads();

    int      cols[4];
    float    cq[4];
    unsigned cnt[4];
    #pragma unroll
    for (int j = 0; j < 4; ++j) {
        int c = cbase + tx * 4 + j;
        cols[j] = c;
        cq[j]   = csq[c];
        cnt[j]  = counts[c];
    }
    #pragma unroll
    for (int i = 0; i < 4; ++i) {
        int r  = rbase + ty * 4 + i;
        int tr = targets[r];
        float lm = 3.0e38f;
        #pragma unroll
        for (int j = 0; j < 4; ++j) {
            float val = cq[j] - 2.0f * acc[i][j];
            if (cols[j] == tr) {
                apval[r] = val;              // exactly one writer per row
            } else if (cnt[j] > 0u) {
                lm = fminf(lm, val);
            }
        }
        if (lm < 3.0e38f) atomicMin(&ldsmin[ty * 4 + i], fkey(lm));
    }
    __syncthreads();
    if (tid < 64) atomicMin(&negmin[rbase + tid], ldsmin[tid]);
}

// Kernel 3: per-row finalize (wave per row). grid = 2048.
__global__ __launch_bounds__(256) void k3_rows(const float* __restrict__ inputs,
                                               const unsigned* __restrict__ negmin,
                                               const float* __restrict__ apval,
                                               float* __restrict__ rowloss,
                                               float* __restrict__ rowprec) {
    const int tid  = threadIdx.x;
    const int wave = tid >> 6;
    const int lane = tid & 63;
    const int r = blockIdx.x * 4 + wave;
    const float4* row = (const float4*)&inputs[(size_t)r * ND];
    float4 v1 = row[lane];
    float4 v2 = row[lane + 64];
    float s = v1.x*v1.x + v1.y*v1.y + v1.z*v1.z + v1.w*v1.w
            + v2.x*v2.x + v2.y*v2.y + v2.z*v2.z + v2.w*v2.w;
    #pragma unroll
    for (int off = 32; off > 0; off >>= 1) s += __shfl_down(s, off);
    if (lane == 0) {
        float an_sq = s + finv(negmin[r]);
        float ap_sq = s + apval[r];
        float an_d = sqrtf(fmaxf(an_sq, 1e-12f));
        float ap_d = sqrtf(fmaxf(ap_sq, 1e-12f));
        rowloss[r] = fmaxf(0.0f, ap_d - an_d + MARGIN_F);
        rowprec[r] = (an_d > ap_d) ? 1.0f : 0.0f;
    }
}

// Kernel 4: final reduction, single block.
__global__ __launch_bounds__(256) void k4_reduce(const float* __restrict__ rowloss,
                                                 const float* __restrict__ rowprec,
                                                 float* __restrict__ out) {
    __shared__ float sl[256];
    __shared__ float sp[256];
    const int tid = threadIdx.x;
    float a = 0.0f, b = 0.0f;
    for (int i = tid; i < NB; i += 256) { a += rowloss[i]; b += rowprec[i]; }
    sl[tid] = a; sp[tid] = b;
    __syncthreads();
    #pragma unroll
    for (int s = 128; s > 0; s >>= 1) {
        if (tid < s) { sl[tid] += sl[tid + s]; sp[tid] += sp[tid + s]; }
        __syncthreads();
    }
    if (tid == 0) {
        out[0] = sl[0] / (float)NB;
        out[1] = sp[0] / (float)NB;
    }
}

extern "C" void kernel_launch(void* const* d_in, const int* in_sizes, int n_in,
                              void* d_out, int out_size, void* d_ws, size_t ws_size,
                              hipStream_t stream) {
    const float* inputs  = (const float*)d_in[0];
    const int*   targets = (const int*)d_in[1];
    const float* centers = (const float*)d_in[2];
    float* out = (float*)d_out;

    unsigned* ws      = (unsigned*)d_ws;
    unsigned* counts  = ws;                       // 512
    float*    csq     = (float*)(ws + 512);       // 512
    unsigned* negmin  = ws + 1024;                // 8192
    float*    apval   = (float*)(ws + 9216);      // 8192
    float*    rowloss = (float*)(ws + 17408);     // 8192
    float*    rowprec = (float*)(ws + 25600);     // 8192

    hipMemsetAsync(counts, 0,    512 * sizeof(unsigned), stream);
    hipMemsetAsync(negmin, 0xFF, NB  * sizeof(unsigned), stream);

    k1_prep<<<128, 256, 0, stream>>>(centers, targets, counts, csq);
    k2_gemm_min<<<dim3(8, 128), 256, 0, stream>>>(inputs, targets, centers,
                                                  counts, csq, negmin, apval);
    k3_rows<<<NB / 4, 256, 0, stream>>>(inputs, negmin, apval, rowloss, rowprec);
    k4_reduce<<<1, 256, 0, stream>>>(rowloss, rowprec, out);
}

// Round 2
// 96.724 us; speedup vs baseline: 1.5245x; 1.5245x over previous
//
#include <hip/hip_runtime.h>
#include <hip/hip_bf16.h>

#define NB 8192   // batch
#define ND 512    // feature dim
#define NC 512    // num classes
#define MARGIN_F 1.0f

typedef __attribute__((ext_vector_type(8))) short bf16x8;   // 8 bf16 (4 VGPRs)
typedef __attribute__((ext_vector_type(4))) float f32x4;    // 4 fp32 acc

__device__ __forceinline__ unsigned fkey(float f) {
    unsigned u = __float_as_uint(f);
    unsigned mask = (u & 0x80000000u) ? 0xFFFFFFFFu : 0x80000000u;
    return u ^ mask;
}
__device__ __forceinline__ float finv(unsigned k) {
    unsigned mask = (k & 0x80000000u) ? 0x80000000u : 0xFFFFFFFFu;
    return __uint_as_float(k ^ mask);
}
__device__ __forceinline__ unsigned short f2bf(float f) {
    __hip_bfloat16 h = __float2bfloat16(f);
    return __builtin_bit_cast(unsigned short, h);
}

#define GLOAD_LDS16(g, l)                                                    \
    __builtin_amdgcn_global_load_lds(                                        \
        (const __attribute__((address_space(1))) void*)(g),                  \
        (__attribute__((address_space(3))) void*)(l), 16, 0, 0)

// -------------------------------------------------------------------------
// k0: fp32->bf16 convert (inputs + centers), row/center sqnorms, negmin init,
//     class histogram (one dedicated block, LDS atomics -> no memset needed).
// grid = 2177 blocks x 256. Blocks [0,2048): inputs, [2048,2176): centers,
// block 2176: histogram.
// -------------------------------------------------------------------------
__global__ __launch_bounds__(256) void k0_prep(
    const float* __restrict__ inputs, const int* __restrict__ targets,
    const float* __restrict__ centers,
    unsigned short* __restrict__ inB, unsigned short* __restrict__ cenB,
    float* __restrict__ rsq, float* __restrict__ csq,
    unsigned* __restrict__ counts, unsigned* __restrict__ negmin)
{
    const int bid = blockIdx.x;
    const int tid = threadIdx.x;

    if (bid == 2176) {   // histogram block
        __shared__ unsigned hist[NC];
        for (int i = tid; i < NC; i += 256) hist[i] = 0u;
        __syncthreads();
        for (int i = tid; i < NB; i += 256) atomicAdd(&hist[targets[i]], 1u);
        __syncthreads();
        for (int i = tid; i < NC; i += 256) counts[i] = hist[i];
        return;
    }

    const int wave = tid >> 6, lane = tid & 63;
    const float* src;
    unsigned short* dst;
    float* sqdst;
    int row;
    bool is_input = (bid < 2048);
    if (is_input) {
        row   = bid * 4 + wave;
        src   = inputs + (size_t)row * ND;
        dst   = inB + (size_t)row * ND;
        sqdst = rsq + row;
    } else {
        row   = (bid - 2048) * 4 + wave;
        src   = centers + (size_t)row * ND;
        dst   = cenB + (size_t)row * ND;
        sqdst = csq + row;
    }

    float4 v1 = ((const float4*)src)[lane];
    float4 v2 = ((const float4*)src)[lane + 64];
    float s = v1.x*v1.x + v1.y*v1.y + v1.z*v1.z + v1.w*v1.w
            + v2.x*v2.x + v2.y*v2.y + v2.z*v2.z + v2.w*v2.w;

    ushort4 o1, o2;
    o1.x = f2bf(v1.x); o1.y = f2bf(v1.y); o1.z = f2bf(v1.z); o1.w = f2bf(v1.w);
    o2.x = f2bf(v2.x); o2.y = f2bf(v2.y); o2.z = f2bf(v2.z); o2.w = f2bf(v2.w);
    ((ushort4*)dst)[lane]      = o1;
    ((ushort4*)dst)[lane + 64] = o2;

    #pragma unroll
    for (int off = 32; off > 0; off >>= 1) s += __shfl_down(s, off);
    if (lane == 0) {
        *sqdst = s;
        if (is_input) negmin[row] = 0xFFFFFFFFu;
    }
}

// -------------------------------------------------------------------------
// k2: bf16 MFMA GEMM (8192x512x512) + fused masked-min / ap-capture epilogue.
// BM=BN=128, BK=32, 512 threads = 8 waves in 2x4 (wave tile 64 rows x 32 cols).
// grid = (4 ctiles, 64 rowtiles) = 256 blocks (1/CU).
// -------------------------------------------------------------------------
__global__ __launch_bounds__(512) void k2_mfma(
    const unsigned short* __restrict__ Ain, const unsigned short* __restrict__ Cen,
    const int* __restrict__ targets, const unsigned* __restrict__ counts,
    const float* __restrict__ csq,
    unsigned* __restrict__ negmin, float* __restrict__ apval)
{
    __shared__ __align__(16) unsigned short As[128 * 32];  // [row][k], row-major, no pad (global_load_lds)
    __shared__ __align__(16) unsigned short Bs[128 * 32];
    __shared__ int      tgtL[128];
    __shared__ float    csqL[128];
    __shared__ unsigned cntL[128];

    const int tid  = threadIdx.x;
    const int w    = tid >> 6;
    const int lane = tid & 63;
    const int wm   = w >> 2;      // 0..1 : row half (64 rows)
    const int wn   = w & 3;       // 0..3 : col quarter (32 cols)
    const int qd   = lane >> 4;   // quad 0..3
    const int ln   = lane & 15;

    const int rbase = blockIdx.y * 128;
    const int cbase = blockIdx.x * 128;

    if (tid < 128) {
        tgtL[tid] = targets[rbase + tid];
        csqL[tid] = csq[cbase + tid];
        cntL[tid] = counts[cbase + tid];
    }

    // staging: wave w stages rows [w*16, w*16+16) of both tiles.
    // lane l -> row w*16 + l/4, cols (l&3)*8 (16 bytes). LDS dest = base + lane*16B.
    const int srow  = w * 16 + (lane >> 2);
    const int scol  = (lane & 3) * 8;
    const unsigned short* gA = Ain + (size_t)(rbase + srow) * ND + scol;
    const unsigned short* gB = Cen + (size_t)(cbase + srow) * ND + scol;
    unsigned short* lA = &As[w * 16 * 32];
    unsigned short* lB = &Bs[w * 16 * 32];

    f32x4 acc[4][2] = {};   // i: 4 row-tiles of 16, j: 2 col-tiles of 16

    for (int kb = 0; kb < ND; kb += 32) {
        __syncthreads();                       // previous iter's ds_reads done
        GLOAD_LDS16(gA + kb, lA);
        GLOAD_LDS16(gB + kb, lB);
        __syncthreads();                       // drains vmcnt -> LDS visible

        bf16x8 a[4], b[2];
        #pragma unroll
        for (int i = 0; i < 4; ++i)
            a[i] = *(const bf16x8*)&As[(wm * 64 + i * 16 + ln) * 32 + qd * 8];
        #pragma unroll
        for (int j = 0; j < 2; ++j)
            b[j] = *(const bf16x8*)&Bs[(wn * 32 + j * 16 + ln) * 32 + qd * 8];
        #pragma unroll
        for (int i = 0; i < 4; ++i)
            #pragma unroll
            for (int j = 0; j < 2; ++j)
                acc[i][j] = __builtin_amdgcn_mfma_f32_16x16x32_bf16(a[i], b[j], acc[i][j], 0, 0, 0);
    }

    // Epilogue. C/D layout: col = lane&15, row = (lane>>4)*4 + reg.
    #pragma unroll
    for (int i = 0; i < 4; ++i) {
        #pragma unroll
        for (int r = 0; r < 4; ++r) {
            const int rlocal = wm * 64 + i * 16 + qd * 4 + r;
            const int grow   = rbase + rlocal;
            const int tr     = tgtL[rlocal];
            float m = 3.0e38f;
            #pragma unroll
            for (int j = 0; j < 2; ++j) {
                const int clocal = wn * 32 + j * 16 + ln;
                const float val = csqL[clocal] - 2.0f * acc[i][j][r];
                if (cbase + clocal == tr) {
                    apval[grow] = val;                 // exactly one writer per row
                } else if (cntL[clocal] > 0u) {
                    m = fminf(m, val);
                }
            }
            #pragma unroll
            for (int off = 1; off < 16; off <<= 1)     // min over the 16 cols in-wave
                m = fminf(m, __shfl_xor(m, off));
            if (ln == 0)
                atomicMin(&negmin[grow], fkey(m));
        }
    }
}

// -------------------------------------------------------------------------
// k3: finalize + reduce, single block (reads only 96 KB of per-row scalars).
// -------------------------------------------------------------------------
__global__ __launch_bounds__(1024) void k3_final(
    const float* __restrict__ rsq, const unsigned* __restrict__ negmin,
    const float* __restrict__ apval, float* __restrict__ out)
{
    __shared__ float sl[1024];
    __shared__ float sp[1024];
    const int tid = threadIdx.x;
    float a = 0.0f, p = 0.0f;
    for (int r = tid; r < NB; r += 1024) {
        float s  = rsq[r];
        float an = sqrtf(fmaxf(s + finv(negmin[r]), 1e-12f));
        float ap = sqrtf(fmaxf(s + apval[r], 1e-12f));
        a += fmaxf(0.0f, ap - an + MARGIN_F);
        p += (an > ap) ? 1.0f : 0.0f;
    }
    sl[tid] = a; sp[tid] = p;
    __syncthreads();
    #pragma unroll
    for (int s = 512; s > 0; s >>= 1) {
        if (tid < s) { sl[tid] += sl[tid + s]; sp[tid] += sp[tid + s]; }
        __syncthreads();
    }
    if (tid == 0) {
        out[0] = sl[0] / (float)NB;
        out[1] = sp[0] / (float)NB;
    }
}

extern "C" void kernel_launch(void* const* d_in, const int* in_sizes, int n_in,
                              void* d_out, int out_size, void* d_ws, size_t ws_size,
                              hipStream_t stream) {
    const float* inputs  = (const float*)d_in[0];
    const int*   targets = (const int*)d_in[1];
    const float* centers = (const float*)d_in[2];
    float* out = (float*)d_out;

    // ws layout (bytes):
    char* w = (char*)d_ws;
    unsigned short* inB    = (unsigned short*)(w);             // 8192*512*2 = 8388608
    unsigned short* cenB   = (unsigned short*)(w + 8388608);   // 512*512*2  = 524288
    float*          rsq    = (float*)(w + 8912896);            // 8192*4
    float*          csqv   = (float*)(w + 8945664);            // 512*4
    unsigned*       counts = (unsigned*)(w + 8947712);         // 512*4
    unsigned*       negmin = (unsigned*)(w + 8949760);         // 8192*4
    float*          apval  = (float*)(w + 8982528);            // 8192*4  (end: 9015296)

    k0_prep<<<2177, 256, 0, stream>>>(inputs, targets, centers,
                                      inB, cenB, rsq, csqv, counts, negmin);
    k2_mfma<<<dim3(4, 64), 512, 0, stream>>>(inB, cenB, targets, counts, csqv,
                                             negmin, apval);
    k3_final<<<1, 1024, 0, stream>>>(rsq, negmin, apval, out);
}